// Round 3
// baseline (46.811 us; speedup 1.0000x reference)
//
#include <hip/hip_runtime.h>
#include <math.h>

#define B_  8
#define L_  4096
#define C_  256

// ======================= Kernel A: conv -> params =========================
// Grid (L_/32, B_), 256 threads. Each wave computes 8 positions' params.
// Output: prm[((b*L + l)*3 + k)] = {floor(pos), alpha, mask, ceil(pos)}
__global__ __launch_bounds__(256)
void params_kernel(const float* __restrict__ x,
                   const float* __restrict__ w_off,
                   const float* __restrict__ b_off,
                   const float* __restrict__ w_mask,
                   const float* __restrict__ b_mask,
                   float4* __restrict__ prm) {
    const int tid  = threadIdx.x;
    const int lane = tid & 63;
    const int w    = tid >> 6;                 // wave 0..3
    const int b    = blockIdx.y;
    const int lbase = blockIdx.x * 32 + w * 8; // first of this wave's 8 positions
    const float* __restrict__ xb = x + (size_t)b * L_ * C_;

    // weights in registers: lane owns channels lane*4 .. lane*4+3
    float w_r[6][12];
    #pragma unroll
    for (int o = 0; o < 6; ++o) {
        const float* ws = (o < 3) ? (w_off + o * (C_ * 3))
                                  : (w_mask + (o - 3) * (C_ * 3));
        const float4* wp = reinterpret_cast<const float4*>(ws + lane * 12);
        float4 q0 = wp[0], q1 = wp[1], q2 = wp[2];
        w_r[o][0]=q0.x; w_r[o][1] =q0.y; w_r[o][2] =q0.z; w_r[o][3] =q0.w;
        w_r[o][4]=q1.x; w_r[o][5] =q1.y; w_r[o][6] =q1.z; w_r[o][7] =q1.w;
        w_r[o][8]=q2.x; w_r[o][9] =q2.y; w_r[o][10]=q2.z; w_r[o][11]=q2.w;
    }

    float acc[8][6];
    #pragma unroll
    for (int i = 0; i < 8; ++i)
        #pragma unroll
        for (int o = 0; o < 6; ++o) acc[i][o] = 0.f;

    // 10 rows cover positions lbase..lbase+7, taps -1..+1 (rows loaded once)
    #pragma unroll
    for (int rr = 0; rr < 10; ++rr) {
        const int row = lbase - 1 + rr;
        if (row >= 0 && row < L_) {
            const float4 xv =
                *reinterpret_cast<const float4*>(xb + (size_t)row * C_ + lane * 4);
            #pragma unroll
            for (int t = 0; t < 3; ++t) {
                const int i = rr - t;               // compile-time per (rr,t)
                if (i >= 0 && i < 8) {
                    #pragma unroll
                    for (int o = 0; o < 6; ++o)
                        acc[i][o] += xv.x * w_r[o][0 + t] + xv.y * w_r[o][3 + t]
                                   + xv.z * w_r[o][6 + t] + xv.w * w_r[o][9 + t];
                }
            }
        }
    }

    // batched butterfly: 48 independent chains per step (pipelined)
    #pragma unroll
    for (int s = 1; s < 64; s <<= 1) {
        #pragma unroll
        for (int i = 0; i < 8; ++i)
            #pragma unroll
            for (int o = 0; o < 6; ++o)
                acc[i][o] += __shfl_xor(acc[i][o], s, 64);
    }

    // lane i*8+k writes params for (position lbase+i, tap k)
    #pragma unroll
    for (int i = 0; i < 8; ++i) {
        const int l = lbase + i;
        #pragma unroll
        for (int k = 0; k < 3; ++k) {
            if (lane == i * 8 + k) {
                float off = acc[i][k] + b_off[k];
                float pos = fminf(fmaxf((float)l + off, 0.0f), (float)(L_ - 1));
                float flf = floorf(pos);
                int   fl  = (int)flf;
                float a   = pos - flf;
                float cef = (float)min(fl + 1, L_ - 1);
                float z   = acc[i][k + 3] + b_mask[k];
                float m   = 1.0f / (1.0f + __expf(-z));
                prm[((size_t)b * L_ + l) * 3 + k] = make_float4(flf, a, m, cef);
            }
        }
    }
}

// ======================= Kernel B: gather + transpose =====================
// Grid (L_/16, B_), 256 threads, LDS 16 KB -> 8 blocks/CU (full occupancy).
#define TLB 16
__global__ __launch_bounds__(256, 8)
void sample_kernel(const float* __restrict__ x,
                   const float4* __restrict__ prm,
                   float* __restrict__ out) {
    __shared__ float s_tile[TLB * C_];   // 16 KB, XOR-swizzled columns

    const int tid = threadIdx.x;
    const int l0  = blockIdx.x * TLB;
    const int b   = blockIdx.y;
    const float* __restrict__ xb = x + (size_t)b * L_ * C_;
    const float4* __restrict__ pb = prm + (size_t)b * L_ * 3;

    // phase 2: thread owns channel c = tid; params are wave-uniform (s_load)
    {
        const int c = tid;
        #pragma unroll
        for (int ll = 0; ll < TLB; ++ll) {
            const int l = l0 + ll;
            float v = 0.f;
            #pragma unroll
            for (int k = 0; k < 3; ++k) {
                const float4 p = pb[l * 3 + k];   // uniform address
                const int fl = (int)p.x;
                const int ce = (int)p.w;
                const float xf = xb[fl * C_ + c];
                const float xc = xb[ce * C_ + c];
                v += (xf + p.y * (xc - xf)) * p.z;
            }
            s_tile[ll * C_ + (c ^ ll)] = v;
        }
    }
    __syncthreads();

    // phase 3: transpose write-out; 16 l-lanes x 16 channel-groups
    {
        const int lw = tid & 15;
        const int cg = tid >> 4;          // 0..15
        #pragma unroll
        for (int cc = 0; cc < 16; ++cc) {
            const int ch = cg * 16 + cc;
            out[((size_t)b * C_ + ch) * L_ + l0 + lw] =
                s_tile[lw * C_ + (ch ^ lw)];
        }
    }
}

// ==================== Fallback: proven R2 fused kernel ====================
#define TL  32
__global__ __launch_bounds__(256, 4)
void dconv1d_fused(const float* __restrict__ x,
                   const float* __restrict__ w_off,
                   const float* __restrict__ b_off,
                   const float* __restrict__ w_mask,
                   const float* __restrict__ b_mask,
                   float* __restrict__ out) {
    __shared__ float s_tile[TL * C_];
    __shared__ int   s_fl[3][TL];
    __shared__ int   s_ce[3][TL];
    __shared__ float s_al[3][TL];
    __shared__ float s_mk[3][TL];

    const int tid  = threadIdx.x;
    const int lane = tid & 63;
    const int g    = tid >> 6;
    const int l0   = blockIdx.x * TL;
    const int b    = blockIdx.y;
    const float* __restrict__ xb = x + (size_t)b * L_ * C_;

    float w_r[6][12];
    #pragma unroll
    for (int o = 0; o < 6; ++o) {
        const float* ws = (o < 3) ? (w_off + o * (C_ * 3))
                                  : (w_mask + (o - 3) * (C_ * 3));
        const float4* wp = reinterpret_cast<const float4*>(ws + lane * 12);
        float4 q0 = wp[0], q1 = wp[1], q2 = wp[2];
        w_r[o][0]=q0.x; w_r[o][1] =q0.y; w_r[o][2] =q0.z; w_r[o][3] =q0.w;
        w_r[o][4]=q1.x; w_r[o][5] =q1.y; w_r[o][6] =q1.z; w_r[o][7] =q1.w;
        w_r[o][8]=q2.x; w_r[o][9] =q2.y; w_r[o][10]=q2.z; w_r[o][11]=q2.w;
    }

    for (int i = 0; i < TL / 4; ++i) {
        const int ll = g * (TL / 4) + i;
        const int l  = l0 + ll;
        float acc[6] = {0.f, 0.f, 0.f, 0.f, 0.f, 0.f};
        #pragma unroll
        for (int t = 0; t < 3; ++t) {
            const int row = l - 1 + t;
            if (row >= 0 && row < L_) {
                const float4 xv =
                    *reinterpret_cast<const float4*>(xb + (size_t)row * C_ + lane * 4);
                #pragma unroll
                for (int o = 0; o < 6; ++o) {
                    acc[o] += xv.x * w_r[o][0 + t] + xv.y * w_r[o][3 + t]
                            + xv.z * w_r[o][6 + t] + xv.w * w_r[o][9 + t];
                }
            }
        }
        #pragma unroll
        for (int o = 0; o < 6; ++o) {
            #pragma unroll
            for (int s = 32; s > 0; s >>= 1)
                acc[o] += __shfl_xor(acc[o], s, 64);
        }
        if (lane == 0) {
            #pragma unroll
            for (int k = 0; k < 3; ++k) {
                float off = acc[k] + b_off[k];
                float pos = fminf(fmaxf((float)l + off, 0.0f), (float)(L_ - 1));
                float flf = floorf(pos);
                int   fl  = (int)flf;
                int   ce  = min(fl + 1, L_ - 1);
                s_fl[k][ll] = fl;
                s_ce[k][ll] = ce;
                s_al[k][ll] = pos - flf;
                float z = acc[k + 3] + b_mask[k];
                s_mk[k][ll] = 1.0f / (1.0f + __expf(-z));
            }
        }
    }
    __syncthreads();

    {
        const int c = tid;
        #pragma unroll 4
        for (int ll = 0; ll < TL; ++ll) {
            float v = 0.f;
            #pragma unroll
            for (int k = 0; k < 3; ++k) {
                const int   fl = s_fl[k][ll];
                const int   ce = s_ce[k][ll];
                const float a  = s_al[k][ll];
                const float m  = s_mk[k][ll];
                const float xf = xb[fl * C_ + c];
                const float xc = xb[ce * C_ + c];
                v += (xf + a * (xc - xf)) * m;
            }
            s_tile[ll * C_ + (c ^ (ll & 31))] = v;
        }
    }
    __syncthreads();

    {
        const int lw = tid & 31;
        const int cg = tid >> 5;
        #pragma unroll 8
        for (int cc = 0; cc < 32; ++cc) {
            const int c = cg * 32 + cc;
            out[((size_t)b * C_ + c) * L_ + l0 + lw] = s_tile[lw * C_ + (c ^ lw)];
        }
    }
}

extern "C" void kernel_launch(void* const* d_in, const int* in_sizes, int n_in,
                              void* d_out, int out_size, void* d_ws, size_t ws_size,
                              hipStream_t stream) {
    const float* x      = (const float*)d_in[0];
    const float* w_off  = (const float*)d_in[1];
    const float* b_off  = (const float*)d_in[2];
    const float* w_mask = (const float*)d_in[3];
    const float* b_mask = (const float*)d_in[4];
    float* out = (float*)d_out;

    const size_t need = (size_t)B_ * L_ * 3 * sizeof(float4);  // 1.57 MB
    if (ws_size >= need) {
        float4* prm = (float4*)d_ws;
        dim3 gA(L_ / 32, B_);
        params_kernel<<<gA, 256, 0, stream>>>(x, w_off, b_off, w_mask, b_mask, prm);
        dim3 gB(L_ / TLB, B_);
        sample_kernel<<<gB, 256, 0, stream>>>(x, prm, out);
    } else {
        dim3 grid(L_ / TL, B_);
        dconv1d_fused<<<grid, 256, 0, stream>>>(x, w_off, b_off, w_mask, b_mask, out);
    }
}

// Round 4
// 43.392 us; speedup vs baseline: 1.0788x; 1.0788x over previous
//
#include <hip/hip_runtime.h>
#include <math.h>

#define B_  8
#define L_  4096
#define C_  256

// ======================= Kernel A: conv -> params =========================
// Grid (L_/16, B_), 256 threads. Each wave computes 4 positions' params.
// Output: prm[((b*L + l)*3 + k)] = {floor(pos), alpha, mask, ceil(pos)}
__global__ __launch_bounds__(256, 4)
void params_kernel(const float* __restrict__ x,
                   const float* __restrict__ w_off,
                   const float* __restrict__ b_off,
                   const float* __restrict__ w_mask,
                   const float* __restrict__ b_mask,
                   float4* __restrict__ prm) {
    const int tid  = threadIdx.x;
    const int lane = tid & 63;
    const int w    = tid >> 6;                 // wave 0..3
    const int b    = blockIdx.y;
    const int lbase = blockIdx.x * 16 + w * 4; // first of this wave's 4 positions
    const float* __restrict__ xb = x + (size_t)b * L_ * C_;

    // weights in registers: lane owns channels lane*4 .. lane*4+3
    float w_r[6][12];
    #pragma unroll
    for (int o = 0; o < 6; ++o) {
        const float* ws = (o < 3) ? (w_off + o * (C_ * 3))
                                  : (w_mask + (o - 3) * (C_ * 3));
        const float4* wp = reinterpret_cast<const float4*>(ws + lane * 12);
        float4 q0 = wp[0], q1 = wp[1], q2 = wp[2];
        w_r[o][0]=q0.x; w_r[o][1] =q0.y; w_r[o][2] =q0.z; w_r[o][3] =q0.w;
        w_r[o][4]=q1.x; w_r[o][5] =q1.y; w_r[o][6] =q1.z; w_r[o][7] =q1.w;
        w_r[o][8]=q2.x; w_r[o][9] =q2.y; w_r[o][10]=q2.z; w_r[o][11]=q2.w;
    }

    float acc[4][6];
    #pragma unroll
    for (int i = 0; i < 4; ++i)
        #pragma unroll
        for (int o = 0; o < 6; ++o) acc[i][o] = 0.f;

    // 6 rows cover positions lbase..lbase+3, taps -1..+1 (rows loaded once)
    #pragma unroll
    for (int rr = 0; rr < 6; ++rr) {
        const int row = lbase - 1 + rr;
        if (row >= 0 && row < L_) {
            const float4 xv =
                *reinterpret_cast<const float4*>(xb + (size_t)row * C_ + lane * 4);
            #pragma unroll
            for (int t = 0; t < 3; ++t) {
                const int i = rr - t;               // compile-time per (rr,t)
                if (i >= 0 && i < 4) {
                    #pragma unroll
                    for (int o = 0; o < 6; ++o)
                        acc[i][o] += xv.x * w_r[o][0 + t] + xv.y * w_r[o][3 + t]
                                   + xv.z * w_r[o][6 + t] + xv.w * w_r[o][9 + t];
                }
            }
        }
    }

    // batched butterfly: 24 independent chains per step (pipelined)
    #pragma unroll
    for (int s = 1; s < 64; s <<= 1) {
        #pragma unroll
        for (int i = 0; i < 4; ++i)
            #pragma unroll
            for (int o = 0; o < 6; ++o)
                acc[i][o] += __shfl_xor(acc[i][o], s, 64);
    }

    // lane i*3+k writes params for (position lbase+i, tap k)
    #pragma unroll
    for (int i = 0; i < 4; ++i) {
        const int l = lbase + i;
        #pragma unroll
        for (int k = 0; k < 3; ++k) {
            if (lane == i * 3 + k) {
                float off = acc[i][k] + b_off[k];
                float pos = fminf(fmaxf((float)l + off, 0.0f), (float)(L_ - 1));
                float flf = floorf(pos);
                int   fl  = (int)flf;
                float a   = pos - flf;
                float cef = (float)min(fl + 1, L_ - 1);
                float z   = acc[i][k + 3] + b_mask[k];
                float m   = 1.0f / (1.0f + __expf(-z));
                prm[((size_t)b * L_ + l) * 3 + k] = make_float4(flf, a, m, cef);
            }
        }
    }
}

// ======================= Kernel B: gather + transpose =====================
// Grid (L_/16, B_), 256 threads, LDS 16 KB -> 8 blocks/CU (full occupancy).
#define TLB 16
__global__ __launch_bounds__(256, 8)
void sample_kernel(const float* __restrict__ x,
                   const float4* __restrict__ prm,
                   float* __restrict__ out) {
    __shared__ float s_tile[TLB * C_];   // 16 KB, XOR-swizzled columns

    const int tid = threadIdx.x;
    const int l0  = blockIdx.x * TLB;
    const int b   = blockIdx.y;
    const float* __restrict__ xb = x + (size_t)b * L_ * C_;
    const float4* __restrict__ pb = prm + (size_t)b * L_ * 3;

    // phase 2: thread owns channel c = tid; params are wave-uniform (s_load)
    {
        const int c = tid;
        #pragma unroll 4
        for (int ll = 0; ll < TLB; ++ll) {
            const int l = l0 + ll;
            float v = 0.f;
            #pragma unroll
            for (int k = 0; k < 3; ++k) {
                const float4 p = pb[l * 3 + k];   // uniform address
                const int fl = (int)p.x;
                const int ce = (int)p.w;
                const float xf = xb[fl * C_ + c];
                const float xc = xb[ce * C_ + c];
                v += (xf + p.y * (xc - xf)) * p.z;
            }
            s_tile[ll * C_ + (c ^ ll)] = v;
        }
    }
    __syncthreads();

    // phase 3: transpose write-out; 16 l-lanes x 16 channel-groups
    {
        const int lw = tid & 15;
        const int cg = tid >> 4;          // 0..15
        #pragma unroll
        for (int cc = 0; cc < 16; ++cc) {
            const int ch = cg * 16 + cc;
            out[((size_t)b * C_ + ch) * L_ + l0 + lw] =
                s_tile[lw * C_ + (ch ^ lw)];
        }
    }
}

// ==================== Fallback: proven R2 fused kernel ====================
#define TL  32
__global__ __launch_bounds__(256, 4)
void dconv1d_fused(const float* __restrict__ x,
                   const float* __restrict__ w_off,
                   const float* __restrict__ b_off,
                   const float* __restrict__ w_mask,
                   const float* __restrict__ b_mask,
                   float* __restrict__ out) {
    __shared__ float s_tile[TL * C_];
    __shared__ int   s_fl[3][TL];
    __shared__ int   s_ce[3][TL];
    __shared__ float s_al[3][TL];
    __shared__ float s_mk[3][TL];

    const int tid  = threadIdx.x;
    const int lane = tid & 63;
    const int g    = tid >> 6;
    const int l0   = blockIdx.x * TL;
    const int b    = blockIdx.y;
    const float* __restrict__ xb = x + (size_t)b * L_ * C_;

    float w_r[6][12];
    #pragma unroll
    for (int o = 0; o < 6; ++o) {
        const float* ws = (o < 3) ? (w_off + o * (C_ * 3))
                                  : (w_mask + (o - 3) * (C_ * 3));
        const float4* wp = reinterpret_cast<const float4*>(ws + lane * 12);
        float4 q0 = wp[0], q1 = wp[1], q2 = wp[2];
        w_r[o][0]=q0.x; w_r[o][1] =q0.y; w_r[o][2] =q0.z; w_r[o][3] =q0.w;
        w_r[o][4]=q1.x; w_r[o][5] =q1.y; w_r[o][6] =q1.z; w_r[o][7] =q1.w;
        w_r[o][8]=q2.x; w_r[o][9] =q2.y; w_r[o][10]=q2.z; w_r[o][11]=q2.w;
    }

    for (int i = 0; i < TL / 4; ++i) {
        const int ll = g * (TL / 4) + i;
        const int l  = l0 + ll;
        float acc[6] = {0.f, 0.f, 0.f, 0.f, 0.f, 0.f};
        #pragma unroll
        for (int t = 0; t < 3; ++t) {
            const int row = l - 1 + t;
            if (row >= 0 && row < L_) {
                const float4 xv =
                    *reinterpret_cast<const float4*>(xb + (size_t)row * C_ + lane * 4);
                #pragma unroll
                for (int o = 0; o < 6; ++o) {
                    acc[o] += xv.x * w_r[o][0 + t] + xv.y * w_r[o][3 + t]
                            + xv.z * w_r[o][6 + t] + xv.w * w_r[o][9 + t];
                }
            }
        }
        #pragma unroll
        for (int o = 0; o < 6; ++o) {
            #pragma unroll
            for (int s = 32; s > 0; s >>= 1)
                acc[o] += __shfl_xor(acc[o], s, 64);
        }
        if (lane == 0) {
            #pragma unroll
            for (int k = 0; k < 3; ++k) {
                float off = acc[k] + b_off[k];
                float pos = fminf(fmaxf((float)l + off, 0.0f), (float)(L_ - 1));
                float flf = floorf(pos);
                int   fl  = (int)flf;
                int   ce  = min(fl + 1, L_ - 1);
                s_fl[k][ll] = fl;
                s_ce[k][ll] = ce;
                s_al[k][ll] = pos - flf;
                float z = acc[k + 3] + b_mask[k];
                s_mk[k][ll] = 1.0f / (1.0f + __expf(-z));
            }
        }
    }
    __syncthreads();

    {
        const int c = tid;
        #pragma unroll 4
        for (int ll = 0; ll < TL; ++ll) {
            float v = 0.f;
            #pragma unroll
            for (int k = 0; k < 3; ++k) {
                const int   fl = s_fl[k][ll];
                const int   ce = s_ce[k][ll];
                const float a  = s_al[k][ll];
                const float m  = s_mk[k][ll];
                const float xf = xb[fl * C_ + c];
                const float xc = xb[ce * C_ + c];
                v += (xf + a * (xc - xf)) * m;
            }
            s_tile[ll * C_ + (c ^ (ll & 31))] = v;
        }
    }
    __syncthreads();

    {
        const int lw = tid & 31;
        const int cg = tid >> 5;
        #pragma unroll 8
        for (int cc = 0; cc < 32; ++cc) {
            const int c = cg * 32 + cc;
            out[((size_t)b * C_ + c) * L_ + l0 + lw] = s_tile[lw * C_ + (c ^ lw)];
        }
    }
}

extern "C" void kernel_launch(void* const* d_in, const int* in_sizes, int n_in,
                              void* d_out, int out_size, void* d_ws, size_t ws_size,
                              hipStream_t stream) {
    const float* x      = (const float*)d_in[0];
    const float* w_off  = (const float*)d_in[1];
    const float* b_off  = (const float*)d_in[2];
    const float* w_mask = (const float*)d_in[3];
    const float* b_mask = (const float*)d_in[4];
    float* out = (float*)d_out;

    const size_t need = (size_t)B_ * L_ * 3 * sizeof(float4);  // 1.57 MB
    if (ws_size >= need) {
        float4* prm = (float4*)d_ws;
        dim3 gA(L_ / 16, B_);
        params_kernel<<<gA, 256, 0, stream>>>(x, w_off, b_off, w_mask, b_mask, prm);
        dim3 gB(L_ / TLB, B_);
        sample_kernel<<<gB, 256, 0, stream>>>(x, prm, out);
    } else {
        dim3 grid(L_ / TL, B_);
        dconv1d_fused<<<grid, 256, 0, stream>>>(x, w_off, b_off, w_mask, b_mask, out);
    }
}